// Round 17
// baseline (238.267 us; speedup 1.0000x reference)
//
#include <hip/hip_runtime.h>

#define B_ 2
#define T_ 2048
#define E_ 1024
#define H_ 16
#define D_ 64
#define DF_ 4096
#define M_ (B_*T_)   // 4096 rows
#define NQKV_ 3072   // fused QKV output width

typedef unsigned short u16;
typedef __attribute__((ext_vector_type(8))) short short8;
typedef __attribute__((ext_vector_type(4))) float f32x4;
typedef __attribute__((ext_vector_type(16))) float f32x16;

__device__ __forceinline__ u16 f2bf(float f) {
  unsigned u = __builtin_bit_cast(unsigned, f);
  u += 0x7FFFu + ((u >> 16) & 1u);   // RNE
  return (u16)(u >> 16);
}
__device__ __forceinline__ unsigned cvtpk(float a, float b) {   // lo=a, hi=b (RNE)
  unsigned r;
  asm("v_cvt_pk_bf16_f32 %0, %1, %2" : "=v"(r) : "v"(a), "v"(b));
  return r;
}
__device__ __forceinline__ float exp2a(float x) {               // 2^x (v_exp_f32)
  float r;
  asm("v_exp_f32 %0, %1" : "=v"(r) : "v"(x));
  return r;
}
__device__ __forceinline__ float bf2f(u16 u) {
  return __builtin_bit_cast(float, (unsigned)u << 16);
}
__device__ __forceinline__ float vmax16(const f32x16& v) {
  float a0 = fmaxf(v[0], v[1]),   a1 = fmaxf(v[2], v[3]);
  float a2 = fmaxf(v[4], v[5]),   a3 = fmaxf(v[6], v[7]);
  float a4 = fmaxf(v[8], v[9]),   a5 = fmaxf(v[10], v[11]);
  float a6 = fmaxf(v[12], v[13]), a7 = fmaxf(v[14], v[15]);
  float b0 = fmaxf(a0, a1), b1 = fmaxf(a2, a3), b2 = fmaxf(a4, a5), b3 = fmaxf(a6, a7);
  return fmaxf(fmaxf(b0, b1), fmaxf(b2, b3));
}
__device__ __forceinline__ float vsum16(const f32x16& v) {
  float a0 = v[0] + v[1],   a1 = v[2] + v[3];
  float a2 = v[4] + v[5],   a3 = v[6] + v[7];
  float a4 = v[8] + v[9],   a5 = v[10] + v[11];
  float a6 = v[12] + v[13], a7 = v[14] + v[15];
  float b0 = a0 + a1, b1 = a2 + a3, b2 = a4 + a5, b3 = a6 + a7;
  return (b0 + b1) + (b2 + b3);
}

// async global->LDS DMA, 16B per lane; LDS dest = wave-uniform base + lane*16
__device__ __forceinline__ void gload_lds16(const u16* g, u16* l) {
  __builtin_amdgcn_global_load_lds((const __attribute__((address_space(1))) void*)g,
                                   (__attribute__((address_space(3))) void*)l, 16, 0, 0);
}

// ---------------- cast fp32 -> bf16 (vectorized x4) ----------------
__global__ __launch_bounds__(256) void cast_bf16_kernel(const float* __restrict__ in,
                                                        u16* __restrict__ out, int n4) {
  int i = blockIdx.x * 256 + threadIdx.x;
  if (i >= n4) return;
  float4 v = ((const float4*)in)[i];
  uint2 r;
  r.x = cvtpk(v.x, v.y);
  r.y = cvtpk(v.z, v.w);
  ((uint2*)out)[i] = r;
}

// ---------------- tiled transpose + cast: in[z][r][c] (f32) -> out[(z*C+c)*outld + r] (bf16)
__global__ __launch_bounds__(256) void transpose_cast_kernel(const float* __restrict__ in,
                                                             u16* __restrict__ out,
                                                             int R, int C, int outld) {
  __shared__ float tile[32][33];
  int z = blockIdx.z;
  int c0 = blockIdx.x * 32, r0 = blockIdx.y * 32;
  int tx = threadIdx.x & 31, ty = threadIdx.x >> 5;
  const float* ip = in + (size_t)z * R * C;
#pragma unroll
  for (int i = 0; i < 32; i += 8)
    tile[ty + i][tx] = ip[(size_t)(r0 + ty + i) * C + (c0 + tx)];
  __syncthreads();
#pragma unroll
  for (int i = 0; i < 32; i += 8)
    out[(size_t)(z * C + c0 + ty + i) * outld + (r0 + tx)] = f2bf(tile[tx][ty + i]);
}

// ---------------- u16 transpose: in[R][C] (row stride ldin) -> out[C][R], 64x64 tiles ----
__global__ __launch_bounds__(256) void transpose_u16_kernel(const u16* __restrict__ in,
                                                            u16* __restrict__ out,
                                                            int R, int C, int ldin) {
  __shared__ __attribute__((aligned(16))) u16 tile[64][72];
  int c0 = blockIdx.x * 64, r0 = blockIdx.y * 64;
  int t = threadIdx.x;
  int tr = t >> 4, tc = (t & 15) * 4;
#pragma unroll
  for (int i = 0; i < 4; i++)
    *(uint2*)&tile[tr + i * 16][tc] = *(const uint2*)&in[(size_t)(r0 + tr + i * 16) * ldin + c0 + tc];
  __syncthreads();
  int rr = (t & 15) * 4, cc0 = t >> 4;
#pragma unroll
  for (int i = 0; i < 4; i++) {
    int cc = cc0 + i * 16;
    u16 a = tile[rr][cc], b = tile[rr + 1][cc], c = tile[rr + 2][cc], d = tile[rr + 3][cc];
    uint2 v;
    v.x = (unsigned)a | ((unsigned)b << 16);
    v.y = (unsigned)c | ((unsigned)d << 16);
    *(uint2*)&out[(size_t)(c0 + cc) * R + r0 + rr] = v;
  }
}

// ---------------- bf16 MFMA GEMM: C[M,N] = A[M,K'] @ Bt[N,K']^T (K-chunk) -------------
// BK=32 / 4-blocks-per-CU variant of the round-10 proven form. TM x TN tile, 4 waves
// (2x2), double-buffered LDS (32KB) via global_load_lds w=16; __launch_bounds__(256,4)
// -> 4 blocks/CU so wave-level TLP hides the per-step barrier drain (m114 mechanism).
// T2 swizzle (rule #21, both-sides): 64B rows = 4 x 16B slots; source pre-swizzle
// slot (l&3)^((l>>2)&3); read slot lg^(lq&3)  => LDS(r,c)=global(r,c^(r&3)),
// b128 reads at the 8-words/bank floor (conflict-free). NO XCD remap (r16: regressed).
template<int TM, int TN, bool BIAS, bool RELU, bool RES, bool OF32, bool OBF>
__global__ __launch_bounds__(256, 4)
void gemm_bt(const u16* __restrict__ A,
             const u16* __restrict__ Bt,
             int M, int N, int K, int lda, int ldb,
             const float* __restrict__ bias,
             const float* __restrict__ res,
             float* __restrict__ outf,
             u16* __restrict__ outb) {
  constexpr int MF = TM / 32;        // m-fragments per wave
  constexpr int NF = TN / 32;        // n-fragments per wave
  constexpr int ACH = TM / 64;       // 16-row staging chunks per wave (A)
  constexpr int BCH = TN / 64;       // (B)
  __shared__ __attribute__((aligned(16))) u16 As[2][TM][32];
  __shared__ __attribute__((aligned(16))) u16 Bs[2][TN][32];
  int m0 = blockIdx.y * TM, n0 = blockIdx.x * TN;
  int z = blockIdx.z;
  A  += (size_t)z * K;                    // split-K chunk offset (0 if gridDim.z==1)
  Bt += (size_t)z * K;
  if (OF32 && outf) outf += (size_t)z * M * N;
  if (OBF && outb)  outb += (size_t)z * M * N;
  int tid = threadIdx.x;
  int lane = tid & 63, w = tid >> 6;
  int wr = w >> 1, wc = w & 1;
  int lg = lane >> 4, lq = lane & 15;
  int srow4 = lane >> 2;                           // 0..15 (row within 16-row chunk)
  int scolsw = ((lane & 3) ^ (srow4 & 3)) * 8;     // pre-swizzled source col (u16)

  const u16* aSrcP[ACH];
  const u16* bSrcP[BCH];
#pragma unroll
  for (int j = 0; j < ACH; j++)
    aSrcP[j] = &A[(size_t)(m0 + w * (ACH * 16) + j * 16 + srow4) * lda + scolsw];
#pragma unroll
  for (int j = 0; j < BCH; j++)
    bSrcP[j] = &Bt[(size_t)(n0 + w * (BCH * 16) + j * 16 + srow4) * ldb + scolsw];

  auto stage = [&](int buf, int k0) {
#pragma unroll
    for (int j = 0; j < ACH; j++)
      gload_lds16(aSrcP[j] + k0, &As[buf][w * (ACH * 16) + j * 16][0]);
#pragma unroll
    for (int j = 0; j < BCH; j++)
      gload_lds16(bSrcP[j] + k0, &Bs[buf][w * (BCH * 16) + j * 16][0]);
  };

  f32x4 acc[MF][NF] = {};
  int csw = (lg ^ (lq & 3)) * 8;                   // swizzled read col (u16)

  stage(0, 0);
  __syncthreads();               // vmcnt(0) drain: buf0 staged
  int cur = 0;
  for (int k0 = 0; k0 < K; k0 += 32) {
    if (k0 + 32 < K) stage(cur ^ 1, k0 + 32);   // prefetch next tile (other buffer)
    short8 af[MF], bf[NF];
#pragma unroll
    for (int m = 0; m < MF; m++) af[m] = *(const short8*)&As[cur][wr * (TM / 2) + m * 16 + lq][csw];
#pragma unroll
    for (int n = 0; n < NF; n++) bf[n] = *(const short8*)&Bs[cur][wc * (TN / 2) + n * 16 + lq][csw];
#pragma unroll
    for (int m = 0; m < MF; m++)
#pragma unroll
      for (int n = 0; n < NF; n++)
        acc[m][n] = __builtin_amdgcn_mfma_f32_16x16x32_bf16(af[m], bf[n], acc[m][n], 0, 0, 0);
    __syncthreads();             // prefetch complete + all reads of cur done
    cur ^= 1;
  }

#pragma unroll
  for (int m = 0; m < MF; m++)
#pragma unroll
    for (int n = 0; n < NF; n++) {
      int row = m0 + wr * (TM / 2) + m * 16 + lg * 4;
      int col = n0 + wc * (TN / 2) + n * 16 + lq;
      float bv = BIAS ? bias[col] : 0.f;
      float vv[4];
#pragma unroll
      for (int r = 0; r < 4; r++) {
        float v = acc[m][n][r];
        if (BIAS) v += bv;
        if (RES)  v += res[(size_t)(row + r) * N + col];
        if (RELU) v = fmaxf(v, 0.f);
        if (OF32) outf[(size_t)(row + r) * N + col] = v;
        vv[r] = v;
      }
      if (OBF) {
        unsigned p01 = cvtpk(vv[0], vv[1]);
        unsigned p23 = cvtpk(vv[2], vv[3]);
        outb[(size_t)(row + 0) * N + col] = (u16)p01;
        outb[(size_t)(row + 1) * N + col] = (u16)(p01 >> 16);
        outb[(size_t)(row + 2) * N + col] = (u16)p23;
        outb[(size_t)(row + 3) * N + col] = (u16)(p23 >> 16);
      }
    }
}

// ---------------- split-K reduce: out = x1 + bf(p0) + bf(p1) + b2 ----------------
// x1 fp32: the residual carry MUST stay fp32 (activations reach the 256-512
// binade where bf16 ulp = 2.0 -> r15's bf16 residual cost 0.57 absmax).
__global__ __launch_bounds__(256) void reduce2_kernel(const float* __restrict__ x1,
                                                      const u16* __restrict__ p0,
                                                      const u16* __restrict__ p1,
                                                      const float* __restrict__ b2,
                                                      float* __restrict__ out) {
  int i = blockIdx.x * 256 + threadIdx.x;   // float4 index; grid covers M_*E_/4
  float4 xv = ((const float4*)x1)[i];
  ushort4 a = ((const ushort4*)p0)[i];
  ushort4 b = ((const ushort4*)p1)[i];
  const float4 bb = *(const float4*)&b2[(i * 4) & (E_ - 1)];
  float4 r;
  r.x = xv.x + bf2f(a.x) + bf2f(b.x) + bb.x;
  r.y = xv.y + bf2f(a.y) + bf2f(b.y) + bb.y;
  r.z = xv.z + bf2f(a.z) + bf2f(b.z) + bb.z;
  r.w = xv.w + bf2f(a.w) + bf2f(b.w) + bb.w;
  ((float4*)out)[i] = r;
}

// ---------------- causal flash attention v7: 8 waves, split-KV, 32x32 MFMA ----------
// (unchanged — pass-verified)
__global__ __launch_bounds__(512, 4) void attn_kernel(const u16* __restrict__ qkv,
                                                      const u16* __restrict__ Vt,
                                                      u16* __restrict__ attn) {
  __shared__ __attribute__((aligned(16))) u16 Ks[2][64 * 64];   // [buf][key][d], swizzled
  __shared__ __attribute__((aligned(16))) u16 Vs[2][64 * 64];   // [buf][d][s],  swizzled
  __shared__ float ml[4][2][32];                                // odd-wave (m,l) per query
  int bid = blockIdx.x;
  int pp = bid >> 8, rrb = bid & 255;
  int h  = rrb >> 4;
  int jj = rrb & 15;
  int b  = pp;
  int qt = pp ? (15 - jj) : jj;   // CU c & c+256 -> complementary work
  int tid = threadIdx.x;
  int lane = tid & 63, w = tid >> 6;      // w in 0..7
  int qg = w & 3;                          // query group (32 queries)
  int par = w >> 2;                        // 0: even key-tiles, 1: odd key-tiles
  int l31 = lane & 31, hh = lane >> 5;
  int q0w = qt * 128 + qg * 32;
  int q_abs = q0w + l31;

  // Q B-fragments: col=q (l31), k = ks*16 + hh*8 + j
  short8 qf[4];
  const u16* Qrow = qkv + (size_t)(b * T_ + q_abs) * NQKV_ + h * 64;
#pragma unroll
  for (int ks = 0; ks < 4; ks++) qf[ks] = *(const short8*)&Qrow[ks * 16 + hh * 8];

  const u16* Kbase  = qkv + (size_t)(b * T_) * NQKV_ + 1024 + h * 64;
  const u16* Vtbase = Vt + (size_t)(h * 64) * M_ + b * T_;

  // staging: 512 uint4 per tile per matrix / 512 threads = 1 each
  int r0s = tid >> 3, c0s = tid & 7;           // rows 0..63
  unsigned kd0 = (unsigned)((r0s * 128 + c0s * 16) ^ ((r0s & 7) << 4));
  const u16* Kg0 = &Kbase[(size_t)r0s * NQKV_ + c0s * 8];
  const u16* Vg0 = &Vtbase[(size_t)r0s * M_ + c0s * 8];

  f32x16 o[2] = {};
  float m_run = -__builtin_inff(), l_run = 0.f;
  const float SCL2 = 0.045084223f;   // (E_^-0.5) * log2(e): exp(x*SCL) = 2^(x*SCL2)
  const int s_stop = qt * 128 + 128; // >= 128 always (>= 2 tiles)

  // prologue: tile 0 -> buf0; tile 1 -> regs; one barrier
  uint4 kr0 = *(const uint4*)Kg0;
  uint4 vr0 = *(const uint4*)Vg0;
  *(uint4*)((char*)&Ks[0][0] + kd0) = kr0;
  *(uint4*)((char*)&Vs[0][0] + kd0) = vr0;
  kr0 = *(const uint4*)&Kg0[(size_t)64 * NQKV_];
  vr0 = *(const uint4*)&Vg0[64];
  __syncthreads();
  int cur = 0;

  for (int s0 = 0; s0 < s_stop; s0 += 64) {
    // ds_write tile t+1 (in regs) into the other buffer; issue loads for t+2
    if (s0 + 64 < s_stop) {
      *(uint4*)((char*)&Ks[cur ^ 1][0] + kd0) = kr0;
      *(uint4*)((char*)&Vs[cur ^ 1][0] + kd0) = vr0;
      if (s0 + 128 < s_stop) {   // loads drain at END-of-iter barrier, after compute
        kr0 = *(const uint4*)&Kg0[(size_t)(s0 + 128) * NQKV_];
        vr0 = *(const uint4*)&Vg0[s0 + 128];
      }
    }

    // my parity, and tile has unmasked keys for this wave (uniform)
    if (((s0 >> 6) & 1) == par && s0 <= q0w + 31) {
      const char* KsC = (const char*)&Ks[cur][0];
      const char* VsC = (const char*)&Vs[cur][0];

      // --- S^T = K @ Q^T : 2 key-chunks of 32, accumulate over 4 d-slices ---
      f32x16 st[2];
      __builtin_amdgcn_s_setprio(1);
#pragma unroll
      for (int c = 0; c < 2; c++) {
        f32x16 acc = {};
        int key = c * 32 + l31;
#pragma unroll
        for (int ks = 0; ks < 4; ks++) {
          unsigned off = (unsigned)((key * 128 + ks * 32 + hh * 16) ^ ((key & 7) << 4));
          short8 kf = *(const short8*)(KsC + off);
          acc = __builtin_amdgcn_mfma_f32_32x32x16_bf16(kf, qf[ks], acc, 0, 0, 0);
        }
        st[c] = acc;
      }
      __builtin_amdgcn_s_setprio(0);

      // --- mask (diagonal tiles only), raw-score domain; tree tile-max ---
      if (s0 + 63 > q0w) {
#pragma unroll
        for (int c = 0; c < 2; c++)
#pragma unroll
          for (int r = 0; r < 16; r++) {
            int key = s0 + c * 32 + (r & 3) + 8 * (r >> 2) + 4 * hh;
            st[c][r] = (key > q_abs) ? -__builtin_inff() : st[c][r];
          }
      }
      float tmax = fmaxf(vmax16(st[0]), vmax16(st[1]));
      tmax = fmaxf(tmax, __shfl_xor(tmax, 32));

      // --- T13 defer-max: rescale only when max grew > 256 raw (= 8 p-exp units) ---
      if (!__all(tmax - m_run <= 256.0f)) {
        float newm = fmaxf(m_run, tmax);
        float fac = exp2a((m_run - newm) * SCL2);
        l_run *= fac;
        o[0] *= fac;
        o[1] *= fac;
        m_run = newm;
      }
      float nm2 = -m_run * SCL2;
#pragma unroll
      for (int c = 0; c < 2; c++)
#pragma unroll
        for (int r = 0; r < 16; r++)
          st[c][r] = exp2a(fmaf(st[c][r], SCL2, nm2));   // exp((s-m)*scale)
      float psum = vsum16(st[0]) + vsum16(st[1]);
      psum += __shfl_xor(psum, 32);
      l_run += psum;

      // --- pack P to bf16 words via v_cvt_pk: wds[c][i] = (p[2i] lo, p[2i+1] hi) ---
      unsigned wds[2][8];
#pragma unroll
      for (int c = 0; c < 2; c++)
#pragma unroll
        for (int i = 0; i < 8; i++)
          wds[c][i] = cvtpk(st[c][2 * i], st[c][2 * i + 1]);

      // --- O^T += V^T @ P^T : 4 key-slices of 16, B-frag built in-register ---
      __builtin_amdgcn_s_setprio(1);
#pragma unroll
      for (int ks16 = 0; ks16 < 4; ks16++) {
        int c = ks16 >> 1, e = ks16 & 1;
        unsigned send0 = hh ? wds[c][4 * e]     : wds[c][4 * e + 2];
        unsigned send1 = hh ? wds[c][4 * e + 1] : wds[c][4 * e + 3];
        unsigned recv0 = (unsigned)__shfl_xor((int)send0, 32);
        unsigned recv1 = (unsigned)__shfl_xor((int)send1, 32);
        uint4 fw;
        fw.x = hh ? recv0 : wds[c][4 * e];
        fw.y = hh ? recv1 : wds[c][4 * e + 1];
        fw.z = hh ? wds[c][4 * e + 2] : recv0;
        fw.w = hh ? wds[c][4 * e + 3] : recv1;
        short8 pf = __builtin_bit_cast(short8, fw);
#pragma unroll
        for (int dc = 0; dc < 2; dc++) {
          int d = dc * 32 + l31;
          unsigned off = (unsigned)((d * 128 + ks16 * 32 + hh * 16) ^ ((d & 7) << 4));
          short8 vf = *(const short8*)(VsC + off);
          o[dc] = __builtin_amdgcn_mfma_f32_32x32x16_bf16(vf, pf, o[dc], 0, 0, 0);
        }
      }
      __builtin_amdgcn_s_setprio(0);
    }

    __syncthreads();             // single barrier: buf^1 visible, buf readers done,
    cur ^= 1;                    // prefetch loads drained AFTER the compute phase
  }

  // ---- split-KV merge: odd waves spill (o,m,l) into dead K/V LDS; even merge ----
  if (w >= 4) {
    char* mb = (w < 6) ? ((char*)&Ks[0][0] + (w - 4) * 8192)
                       : ((char*)&Vs[0][0] + (w - 6) * 8192);
#pragma unroll
    for (int g = 0; g < 8; g++) {
      float4 v4;
      v4.x = o[g >> 2][(g & 3) * 4];
      v4.y = o[g >> 2][(g & 3) * 4 + 1];
      v4.z = o[g >> 2][(g & 3) * 4 + 2];
      v4.w = o[g >> 2][(g & 3) * 4 + 3];
      *(float4*)(mb + g * 1024 + lane * 16) = v4;
    }
    if (hh == 0) {
      ml[qg][0][l31] = m_run;
      ml[qg][1][l31] = l_run;
    }
  }
  __syncthreads();
  if (w < 4) {
    const char* mb = (qg < 2) ? ((const char*)&Ks[0][0] + qg * 8192)
                              : ((const char*)&Vs[0][0] + (qg - 2) * 8192);
    float m1 = ml[qg][0][l31];
    float l1 = ml[qg][1][l31];
    float mn = fmaxf(m_run, m1);
    float f0 = exp2a((m_run - mn) * SCL2);
    float f1 = exp2a((m1 - mn) * SCL2);
    float ln = l_run * f0 + l1 * f1;
    float inv = 1.f / ln;
    float g0 = f0 * inv, g1 = f1 * inv;
    const size_t orow = (size_t)(b * T_ + q_abs) * E_ + h * 64;
#pragma unroll
    for (int g = 0; g < 8; g++) {
      float4 o1 = *(const float4*)(mb + g * 1024 + lane * 16);
      int dc = g >> 2, a = g & 3;
      float e0 = o[dc][4 * a]     * g0 + o1.x * g1;
      float e1 = o[dc][4 * a + 1] * g0 + o1.y * g1;
      float e2 = o[dc][4 * a + 2] * g0 + o1.z * g1;
      float e3 = o[dc][4 * a + 3] * g0 + o1.w * g1;
      uint2 r;
      r.x = cvtpk(e0, e1);
      r.y = cvtpk(e2, e3);
      *(uint2*)&attn[orow + dc * 32 + 8 * a + 4 * hh] = r;
    }
  }
}

// ---------------- launch ----------------
extern "C" void kernel_launch(void* const* d_in, const int* in_sizes, int n_in,
                              void* d_out, int out_size, void* d_ws, size_t ws_size,
                              hipStream_t stream) {
  const float* x  = (const float*)d_in[0];
  const float* Wq = (const float*)d_in[1];
  const float* Wk = (const float*)d_in[2];
  const float* Wv = (const float*)d_in[3];
  const float* Wo = (const float*)d_in[4];
  const float* bo = (const float*)d_in[5];
  const float* W1 = (const float*)d_in[6];
  const float* b1 = (const float*)d_in[7];
  const float* W2 = (const float*)d_in[8];
  const float* b2 = (const float*)d_in[9];
  float* out = (float*)d_out;

  const size_t MB = 1048576;
  char* ws = (char*)d_ws;
  u16* xb    = (u16*)(ws + 0);          // 8MB   (x1b aliases; pbuf aliases at FFN2)
  u16* WqkvT = (u16*)(ws + 8 * MB);     // 6MB   (dead after QKV; pbuf tail)
  u16* WoT   = (u16*)(ws + 14 * MB);    // 2MB   (dead after proj; pbuf tail)
  u16* W1T   = (u16*)(ws + 16 * MB);    // 8MB   (dead after FFN1)
  u16* W2T   = (u16*)(ws + 24 * MB);    // 8MB   (live through FFN2)
  u16* qkv   = (u16*)(ws + 32 * MB);    // 24MB  (dead after attn)
  u16* attn  = (u16*)(ws + 56 * MB);    // 8MB   (dead after proj)
  float* x1  = (float*)(ws + 64 * MB);  // 16MB  fp32 residual (written by proj, Vt dead)
  u16* Vtb   = (u16*)(ws + 64 * MB);    // 8MB   overlaps x1 (dead before x1 written)
  u16* x1b   = (u16*)(ws + 0);          // alias xb (FFN1 input; dead after FFN1)
  u16* hbuf  = (u16*)(ws + 32 * MB);    // 32MB  alias qkv+attn (FFN2 input)
  u16* pbuf  = (u16*)(ws + 0);          // 16MB  FFN2 split-K partials (x1b dead then)

  // prep: cast + weight transposes to [N][K] bf16
  cast_bf16_kernel<<<(M_ * E_ / 4 + 255) / 256, 256, 0, stream>>>(x, xb, M_ * E_ / 4);
  transpose_cast_kernel<<<dim3(2, 32, 16),  256, 0, stream>>>(Wq, WqkvT,                E_, D_, E_);
  transpose_cast_kernel<<<dim3(2, 32, 16),  256, 0, stream>>>(Wk, WqkvT + 1024 * 1024,  E_, D_, E_);
  transpose_cast_kernel<<<dim3(2, 32, 16),  256, 0, stream>>>(Wv, WqkvT + 2048 * 1024,  E_, D_, E_);
  transpose_cast_kernel<<<dim3(32, 32, 1),  256, 0, stream>>>(Wo, WoT, E_, E_, E_);
  transpose_cast_kernel<<<dim3(128, 32, 1), 256, 0, stream>>>(W1, W1T, E_, DF_, E_);
  transpose_cast_kernel<<<dim3(32, 128, 1), 256, 0, stream>>>(W2, W2T, DF_, E_, DF_);

  // fused QKV GEMM: qkv[M][3072]  (768 blocks, up to 4/CU now)
  gemm_bt<128,128,false,false,false,false,true><<<dim3(NQKV_ / 128, M_ / 128), 256, 0, stream>>>(
      xb, WqkvT, M_, NQKV_, E_, E_, E_, nullptr, nullptr, nullptr, qkv);

  // V -> V^T  (qkv cols 2048..3071 -> Vt[E][M])
  transpose_u16_kernel<<<dim3(E_ / 64, M_ / 64), 256, 0, stream>>>(qkv + 2048, Vtb, M_, E_, NQKV_);

  attn_kernel<<<B_ * H_ * (T_ / 128), 512, 0, stream>>>(qkv, Vtb, attn);

  // x1 = x + attn @ Wo + bo  (fp32 residual + bf16 mirror for FFN1)
  gemm_bt<64,128,true,false,true,true,true><<<dim3(E_ / 128, M_ / 64), 256, 0, stream>>>(
      attn, WoT, M_, E_, E_, E_, E_, bo, x, x1, x1b);
  // h = relu(x1 @ W1 + b1)  (1024 blocks, 4/CU)
  gemm_bt<128,128,true,true,false,false,true><<<dim3(DF_ / 128, M_ / 128), 256, 0, stream>>>(
      x1b, W1T, M_, DF_, E_, E_, E_, b1, nullptr, nullptr, hbuf);
  // FFN2 split-K: p[z] = h[:, z*2048:] @ W2T[:, z*2048:]^T  (bf16 partials, 512 blocks)
  gemm_bt<128,128,false,false,false,false,true><<<dim3(E_ / 128, M_ / 128, 2), 256, 0, stream>>>(
      hbuf, W2T, M_, E_, DF_ / 2, DF_, DF_, nullptr, nullptr, nullptr, pbuf);
  // out = x1 + p0 + p1 + b2
  reduce2_kernel<<<M_ * E_ / 4 / 256, 256, 0, stream>>>(x1, pbuf, pbuf + (size_t)M_ * E_, b2, out);
}

// Round 19
// 226.076 us; speedup vs baseline: 1.0539x; 1.0539x over previous
//
#include <hip/hip_runtime.h>

#define B_ 2
#define T_ 2048
#define E_ 1024
#define H_ 16
#define D_ 64
#define DF_ 4096
#define M_ (B_*T_)   // 4096 rows
#define NQKV_ 3072   // fused QKV output width

typedef unsigned short u16;
typedef __attribute__((ext_vector_type(8))) short short8;
typedef __attribute__((ext_vector_type(4))) float f32x4;
typedef __attribute__((ext_vector_type(16))) float f32x16;

__device__ __forceinline__ u16 f2bf(float f) {
  unsigned u = __builtin_bit_cast(unsigned, f);
  u += 0x7FFFu + ((u >> 16) & 1u);   // RNE
  return (u16)(u >> 16);
}
__device__ __forceinline__ unsigned cvtpk(float a, float b) {   // lo=a, hi=b (RNE)
  unsigned r;
  asm("v_cvt_pk_bf16_f32 %0, %1, %2" : "=v"(r) : "v"(a), "v"(b));
  return r;
}
__device__ __forceinline__ float exp2a(float x) {               // 2^x (v_exp_f32)
  float r;
  asm("v_exp_f32 %0, %1" : "=v"(r) : "v"(x));
  return r;
}
__device__ __forceinline__ float bf2f(u16 u) {
  return __builtin_bit_cast(float, (unsigned)u << 16);
}
__device__ __forceinline__ float vmax16(const f32x16& v) {
  float a0 = fmaxf(v[0], v[1]),   a1 = fmaxf(v[2], v[3]);
  float a2 = fmaxf(v[4], v[5]),   a3 = fmaxf(v[6], v[7]);
  float a4 = fmaxf(v[8], v[9]),   a5 = fmaxf(v[10], v[11]);
  float a6 = fmaxf(v[12], v[13]), a7 = fmaxf(v[14], v[15]);
  float b0 = fmaxf(a0, a1), b1 = fmaxf(a2, a3), b2 = fmaxf(a4, a5), b3 = fmaxf(a6, a7);
  return fmaxf(fmaxf(b0, b1), fmaxf(b2, b3));
}
__device__ __forceinline__ float vsum16(const f32x16& v) {
  float a0 = v[0] + v[1],   a1 = v[2] + v[3];
  float a2 = v[4] + v[5],   a3 = v[6] + v[7];
  float a4 = v[8] + v[9],   a5 = v[10] + v[11];
  float a6 = v[12] + v[13], a7 = v[14] + v[15];
  float b0 = a0 + a1, b1 = a2 + a3, b2 = a4 + a5, b3 = a6 + a7;
  return (b0 + b1) + (b2 + b3);
}

// async global->LDS DMA, 16B per lane; LDS dest = wave-uniform base + lane*16
__device__ __forceinline__ void gload_lds16(const u16* g, u16* l) {
  __builtin_amdgcn_global_load_lds((const __attribute__((address_space(1))) void*)g,
                                   (__attribute__((address_space(3))) void*)l, 16, 0, 0);
}

// ---------------- cast fp32 -> bf16 (vectorized x4) ----------------
__global__ __launch_bounds__(256) void cast_bf16_kernel(const float* __restrict__ in,
                                                        u16* __restrict__ out, int n4) {
  int i = blockIdx.x * 256 + threadIdx.x;
  if (i >= n4) return;
  float4 v = ((const float4*)in)[i];
  uint2 r;
  r.x = cvtpk(v.x, v.y);
  r.y = cvtpk(v.z, v.w);
  ((uint2*)out)[i] = r;
}

// ---------------- tiled transpose + cast: in[z][r][c] (f32) -> out[(z*C+c)*outld + r] (bf16)
__global__ __launch_bounds__(256) void transpose_cast_kernel(const float* __restrict__ in,
                                                             u16* __restrict__ out,
                                                             int R, int C, int outld) {
  __shared__ float tile[32][33];
  int z = blockIdx.z;
  int c0 = blockIdx.x * 32, r0 = blockIdx.y * 32;
  int tx = threadIdx.x & 31, ty = threadIdx.x >> 5;
  const float* ip = in + (size_t)z * R * C;
#pragma unroll
  for (int i = 0; i < 32; i += 8)
    tile[ty + i][tx] = ip[(size_t)(r0 + ty + i) * C + (c0 + tx)];
  __syncthreads();
#pragma unroll
  for (int i = 0; i < 32; i += 8)
    out[(size_t)(z * C + c0 + ty + i) * outld + (r0 + tx)] = f2bf(tile[tx][ty + i]);
}

// ---------------- bf16 MFMA GEMM: C[M,N] = A[M,K'] @ Bt[N,K']^T (K-chunk) -------------
// ROUND-14 PROVEN FORM (230.2us). TM x TN tile, 4 waves (2x2), BK=64, double-buffered
// LDS via global_load_lds w=16; T2 swizzle via pre-swizzled GLOBAL source (lds dest
// linear, rule #21); 2-phase __syncthreads pipeline. NO XCD remap (r16: regressed);
// BK=64 @ 2 blocks/CU (r17: BK=32@4 regressed).
// VSPLIT (QKV only): output cols >= 2048 are the V head block -> written TRANSPOSED
// to vtb[col-2048][row..row+3] (uint2, rows 4-aligned), fusing the V-transpose.
template<int TM, int TN, bool BIAS, bool RELU, bool RES, bool OF32, bool OBF, bool VSPLIT>
__global__ __launch_bounds__(256, 2)
void gemm_bt(const u16* __restrict__ A,
             const u16* __restrict__ Bt,
             int M, int N, int K, int lda, int ldb,
             const float* __restrict__ bias,
             const float* __restrict__ res,
             float* __restrict__ outf,
             u16* __restrict__ outb,
             u16* __restrict__ vtb) {
  constexpr int MF = TM / 32;        // m-fragments per wave
  constexpr int NF = TN / 32;        // n-fragments per wave
  constexpr int ACH = TM / 32;       // 8-row staging chunks per wave (A)
  constexpr int BCH = TN / 32;       // (B)
  __shared__ __attribute__((aligned(16))) u16 As[2][TM][64];
  __shared__ __attribute__((aligned(16))) u16 Bs[2][TN][64];
  int m0 = blockIdx.y * TM, n0 = blockIdx.x * TN;
  int z = blockIdx.z;
  A  += (size_t)z * K;                    // split-K chunk offset (0 if gridDim.z==1)
  Bt += (size_t)z * K;
  if (OF32 && outf) outf += (size_t)z * M * N;
  if (OBF && outb)  outb += (size_t)z * M * N;
  int tid = threadIdx.x;
  int lane = tid & 63, w = tid >> 6;
  int wr = w >> 1, wc = w & 1;
  int lg = lane >> 4, lq = lane & 15;
  int srow8 = lane >> 3;
  int scolsw = ((lane & 7) ^ srow8) * 8;   // pre-swizzled source col (u16)

  const u16* aSrcP[ACH];
  const u16* bSrcP[BCH];
#pragma unroll
  for (int j = 0; j < ACH; j++)
    aSrcP[j] = &A[(size_t)(m0 + w * (ACH * 8) + j * 8 + srow8) * lda + scolsw];
#pragma unroll
  for (int j = 0; j < BCH; j++)
    bSrcP[j] = &Bt[(size_t)(n0 + w * (BCH * 8) + j * 8 + srow8) * ldb + scolsw];

  auto stage = [&](int buf, int k0) {
#pragma unroll
    for (int j = 0; j < ACH; j++)
      gload_lds16(aSrcP[j] + k0, &As[buf][w * (ACH * 8) + j * 8][0]);
#pragma unroll
    for (int j = 0; j < BCH; j++)
      gload_lds16(bSrcP[j] + k0, &Bs[buf][w * (BCH * 8) + j * 8][0]);
  };

  f32x4 acc[MF][NF] = {};
  int lqx = lq & 7;

  stage(0, 0);
  __syncthreads();               // vmcnt(0) drain: buf0 staged
  int cur = 0;
  for (int k0 = 0; k0 < K; k0 += 64) {
    if (k0 + 64 < K) stage(cur ^ 1, k0 + 64);   // prefetch next tile (other buffer)
#pragma unroll
    for (int kk = 0; kk < 2; kk++) {
      short8 af[MF], bf[NF];
      int csw = ((lg + kk * 4) ^ lqx) * 8;      // swizzled read col (u16)
#pragma unroll
      for (int m = 0; m < MF; m++) af[m] = *(const short8*)&As[cur][wr * (TM / 2) + m * 16 + lq][csw];
#pragma unroll
      for (int n = 0; n < NF; n++) bf[n] = *(const short8*)&Bs[cur][wc * (TN / 2) + n * 16 + lq][csw];
#pragma unroll
      for (int m = 0; m < MF; m++)
#pragma unroll
        for (int n = 0; n < NF; n++)
          acc[m][n] = __builtin_amdgcn_mfma_f32_16x16x32_bf16(af[m], bf[n], acc[m][n], 0, 0, 0);
    }
    __syncthreads();             // prefetch complete + all reads of cur done
    cur ^= 1;
  }

#pragma unroll
  for (int m = 0; m < MF; m++)
#pragma unroll
    for (int n = 0; n < NF; n++) {
      int row = m0 + wr * (TM / 2) + m * 16 + lg * 4;
      int col = n0 + wc * (TN / 2) + n * 16 + lq;
      float bv = BIAS ? bias[col] : 0.f;
      float vv[4];
#pragma unroll
      for (int r = 0; r < 4; r++) {
        float v = acc[m][n][r];
        if (BIAS) v += bv;
        if (RES)  v += res[(size_t)(row + r) * N + col];
        if (RELU) v = fmaxf(v, 0.f);
        if (OF32) outf[(size_t)(row + r) * N + col] = v;
        vv[r] = v;
      }
      if (OBF) {
        unsigned p01 = cvtpk(vv[0], vv[1]);
        unsigned p23 = cvtpk(vv[2], vv[3]);
        if (VSPLIT && n0 >= 2048) {
          // V head block: write transposed Vt[col-2048][row..row+3] (8B aligned)
          uint2 rr; rr.x = p01; rr.y = p23;
          *(uint2*)&vtb[(size_t)(col - 2048) * M + row] = rr;
        } else {
          outb[(size_t)(row + 0) * N + col] = (u16)p01;
          outb[(size_t)(row + 1) * N + col] = (u16)(p01 >> 16);
          outb[(size_t)(row + 2) * N + col] = (u16)p23;
          outb[(size_t)(row + 3) * N + col] = (u16)(p23 >> 16);
        }
      }
    }
}

// ---------------- split-K reduce: out = x1 + bf(p0) + bf(p1) + b2 ----------------
// x1 fp32: the residual carry MUST stay fp32 (activations reach the 256-512
// binade where bf16 ulp = 2.0 -> r15's bf16 residual cost 0.57 absmax).
__global__ __launch_bounds__(256) void reduce2_kernel(const float* __restrict__ x1,
                                                      const u16* __restrict__ p0,
                                                      const u16* __restrict__ p1,
                                                      const float* __restrict__ b2,
                                                      float* __restrict__ out) {
  int i = blockIdx.x * 256 + threadIdx.x;   // float4 index; grid covers M_*E_/4
  float4 xv = ((const float4*)x1)[i];
  ushort4 a = ((const ushort4*)p0)[i];
  ushort4 b = ((const ushort4*)p1)[i];
  const float4 bb = *(const float4*)&b2[(i * 4) & (E_ - 1)];
  float4 r;
  r.x = xv.x + bf2f(a.x) + bf2f(b.x) + bb.x;
  r.y = xv.y + bf2f(a.y) + bf2f(b.y) + bb.y;
  r.z = xv.z + bf2f(a.z) + bf2f(b.z) + bb.z;
  r.w = xv.w + bf2f(a.w) + bf2f(b.w) + bb.w;
  ((float4*)out)[i] = r;
}

// ---------------- causal flash attention v7: 8 waves, split-KV, 32x32 MFMA ----------
// (unchanged — pass-verified at 230us)
__global__ __launch_bounds__(512, 4) void attn_kernel(const u16* __restrict__ qkv,
                                                      const u16* __restrict__ Vt,
                                                      u16* __restrict__ attn) {
  __shared__ __attribute__((aligned(16))) u16 Ks[2][64 * 64];   // [buf][key][d], swizzled
  __shared__ __attribute__((aligned(16))) u16 Vs[2][64 * 64];   // [buf][d][s],  swizzled
  __shared__ float ml[4][2][32];                                // odd-wave (m,l) per query
  int bid = blockIdx.x;
  int pp = bid >> 8, rrb = bid & 255;
  int h  = rrb >> 4;
  int jj = rrb & 15;
  int b  = pp;
  int qt = pp ? (15 - jj) : jj;   // CU c & c+256 -> complementary work
  int tid = threadIdx.x;
  int lane = tid & 63, w = tid >> 6;      // w in 0..7
  int qg = w & 3;                          // query group (32 queries)
  int par = w >> 2;                        // 0: even key-tiles, 1: odd key-tiles
  int l31 = lane & 31, hh = lane >> 5;
  int q0w = qt * 128 + qg * 32;
  int q_abs = q0w + l31;

  // Q B-fragments: col=q (l31), k = ks*16 + hh*8 + j
  short8 qf[4];
  const u16* Qrow = qkv + (size_t)(b * T_ + q_abs) * NQKV_ + h * 64;
#pragma unroll
  for (int ks = 0; ks < 4; ks++) qf[ks] = *(const short8*)&Qrow[ks * 16 + hh * 8];

  const u16* Kbase  = qkv + (size_t)(b * T_) * NQKV_ + 1024 + h * 64;
  const u16* Vtbase = Vt + (size_t)(h * 64) * M_ + b * T_;

  // staging: 512 uint4 per tile per matrix / 512 threads = 1 each
  int r0s = tid >> 3, c0s = tid & 7;           // rows 0..63
  unsigned kd0 = (unsigned)((r0s * 128 + c0s * 16) ^ ((r0s & 7) << 4));
  const u16* Kg0 = &Kbase[(size_t)r0s * NQKV_ + c0s * 8];
  const u16* Vg0 = &Vtbase[(size_t)r0s * M_ + c0s * 8];

  f32x16 o[2] = {};
  float m_run = -__builtin_inff(), l_run = 0.f;
  const float SCL2 = 0.045084223f;   // (E_^-0.5) * log2(e): exp(x*SCL) = 2^(x*SCL2)
  const int s_stop = qt * 128 + 128; // >= 128 always (>= 2 tiles)

  // prologue: tile 0 -> buf0; tile 1 -> regs; one barrier
  uint4 kr0 = *(const uint4*)Kg0;
  uint4 vr0 = *(const uint4*)Vg0;
  *(uint4*)((char*)&Ks[0][0] + kd0) = kr0;
  *(uint4*)((char*)&Vs[0][0] + kd0) = vr0;
  kr0 = *(const uint4*)&Kg0[(size_t)64 * NQKV_];
  vr0 = *(const uint4*)&Vg0[64];
  __syncthreads();
  int cur = 0;

  for (int s0 = 0; s0 < s_stop; s0 += 64) {
    // ds_write tile t+1 (in regs) into the other buffer; issue loads for t+2
    if (s0 + 64 < s_stop) {
      *(uint4*)((char*)&Ks[cur ^ 1][0] + kd0) = kr0;
      *(uint4*)((char*)&Vs[cur ^ 1][0] + kd0) = vr0;
      if (s0 + 128 < s_stop) {   // loads drain at END-of-iter barrier, after compute
        kr0 = *(const uint4*)&Kg0[(size_t)(s0 + 128) * NQKV_];
        vr0 = *(const uint4*)&Vg0[s0 + 128];
      }
    }

    // my parity, and tile has unmasked keys for this wave (uniform)
    if (((s0 >> 6) & 1) == par && s0 <= q0w + 31) {
      const char* KsC = (const char*)&Ks[cur][0];
      const char* VsC = (const char*)&Vs[cur][0];

      // --- S^T = K @ Q^T : 2 key-chunks of 32, accumulate over 4 d-slices ---
      f32x16 st[2];
      __builtin_amdgcn_s_setprio(1);
#pragma unroll
      for (int c = 0; c < 2; c++) {
        f32x16 acc = {};
        int key = c * 32 + l31;
#pragma unroll
        for (int ks = 0; ks < 4; ks++) {
          unsigned off = (unsigned)((key * 128 + ks * 32 + hh * 16) ^ ((key & 7) << 4));
          short8 kf = *(const short8*)(KsC + off);
          acc = __builtin_amdgcn_mfma_f32_32x32x16_bf16(kf, qf[ks], acc, 0, 0, 0);
        }
        st[c] = acc;
      }
      __builtin_amdgcn_s_setprio(0);

      // --- mask (diagonal tiles only), raw-score domain; tree tile-max ---
      if (s0 + 63 > q0w) {
#pragma unroll
        for (int c = 0; c < 2; c++)
#pragma unroll
          for (int r = 0; r < 16; r++) {
            int key = s0 + c * 32 + (r & 3) + 8 * (r >> 2) + 4 * hh;
            st[c][r] = (key > q_abs) ? -__builtin_inff() : st[c][r];
          }
      }
      float tmax = fmaxf(vmax16(st[0]), vmax16(st[1]));
      tmax = fmaxf(tmax, __shfl_xor(tmax, 32));

      // --- T13 defer-max: rescale only when max grew > 256 raw (= 8 p-exp units) ---
      if (!__all(tmax - m_run <= 256.0f)) {
        float newm = fmaxf(m_run, tmax);
        float fac = exp2a((m_run - newm) * SCL2);
        l_run *= fac;
        o[0] *= fac;
        o[1] *= fac;
        m_run = newm;
      }
      float nm2 = -m_run * SCL2;
#pragma unroll
      for (int c = 0; c < 2; c++)
#pragma unroll
        for (int r = 0; r < 16; r++)
          st[c][r] = exp2a(fmaf(st[c][r], SCL2, nm2));   // exp((s-m)*scale)
      float psum = vsum16(st[0]) + vsum16(st[1]);
      psum += __shfl_xor(psum, 32);
      l_run += psum;

      // --- pack P to bf16 words via v_cvt_pk: wds[c][i] = (p[2i] lo, p[2i+1] hi) ---
      unsigned wds[2][8];
#pragma unroll
      for (int c = 0; c < 2; c++)
#pragma unroll
        for (int i = 0; i < 8; i++)
          wds[c][i] = cvtpk(st[c][2 * i], st[c][2 * i + 1]);

      // --- O^T += V^T @ P^T : 4 key-slices of 16, B-frag built in-register ---
      __builtin_amdgcn_s_setprio(1);
#pragma unroll
      for (int ks16 = 0; ks16 < 4; ks16++) {
        int c = ks16 >> 1, e = ks16 & 1;
        unsigned send0 = hh ? wds[c][4 * e]     : wds[c][4 * e + 2];
        unsigned send1 = hh ? wds[c][4 * e + 1] : wds[c][4 * e + 3];
        unsigned recv0 = (unsigned)__shfl_xor((int)send0, 32);
        unsigned recv1 = (unsigned)__shfl_xor((int)send1, 32);
        uint4 fw;
        fw.x = hh ? recv0 : wds[c][4 * e];
        fw.y = hh ? recv1 : wds[c][4 * e + 1];
        fw.z = hh ? wds[c][4 * e + 2] : recv0;
        fw.w = hh ? wds[c][4 * e + 3] : recv1;
        short8 pf = __builtin_bit_cast(short8, fw);
#pragma unroll
        for (int dc = 0; dc < 2; dc++) {
          int d = dc * 32 + l31;
          unsigned off = (unsigned)((d * 128 + ks16 * 32 + hh * 16) ^ ((d & 7) << 4));
          short8 vf = *(const short8*)(VsC + off);
          o[dc] = __builtin_amdgcn_mfma_f32_32x32x16_bf16(vf, pf, o[dc], 0, 0, 0);
        }
      }
      __builtin_amdgcn_s_setprio(0);
    }

    __syncthreads();             // single barrier: buf^1 visible, buf readers done,
    cur ^= 1;                    // prefetch loads drained AFTER the compute phase
  }

  // ---- split-KV merge: odd waves spill (o,m,l) into dead K/V LDS; even merge ----
  if (w >= 4) {
    char* mb = (w < 6) ? ((char*)&Ks[0][0] + (w - 4) * 8192)
                       : ((char*)&Vs[0][0] + (w - 6) * 8192);
#pragma unroll
    for (int g = 0; g < 8; g++) {
      float4 v4;
      v4.x = o[g >> 2][(g & 3) * 4];
      v4.y = o[g >> 2][(g & 3) * 4 + 1];
      v4.z = o[g >> 2][(g & 3) * 4 + 2];
      v4.w = o[g >> 2][(g & 3) * 4 + 3];
      *(float4*)(mb + g * 1024 + lane * 16) = v4;
    }
    if (hh == 0) {
      ml[qg][0][l31] = m_run;
      ml[qg][1][l31] = l_run;
    }
  }
  __syncthreads();
  if (w < 4) {
    const char* mb = (qg < 2) ? ((const char*)&Ks[0][0] + qg * 8192)
                              : ((const char*)&Vs[0][0] + (qg - 2) * 8192);
    float m1 = ml[qg][0][l31];
    float l1 = ml[qg][1][l31];
    float mn = fmaxf(m_run, m1);
    float f0 = exp2a((m_run - mn) * SCL2);
    float f1 = exp2a((m1 - mn) * SCL2);
    float ln = l_run * f0 + l1 * f1;
    float inv = 1.f / ln;
    float g0 = f0 * inv, g1 = f1 * inv;
    const size_t orow = (size_t)(b * T_ + q_abs) * E_ + h * 64;
#pragma unroll
    for (int g = 0; g < 8; g++) {
      float4 o1 = *(const float4*)(mb + g * 1024 + lane * 16);
      int dc = g >> 2, a = g & 3;
      float e0 = o[dc][4 * a]     * g0 + o1.x * g1;
      float e1 = o[dc][4 * a + 1] * g0 + o1.y * g1;
      float e2 = o[dc][4 * a + 2] * g0 + o1.z * g1;
      float e3 = o[dc][4 * a + 3] * g0 + o1.w * g1;
      uint2 r;
      r.x = cvtpk(e0, e1);
      r.y = cvtpk(e2, e3);
      *(uint2*)&attn[orow + dc * 32 + 8 * a + 4 * hh] = r;
    }
  }
}

// ---------------- launch ----------------
extern "C" void kernel_launch(void* const* d_in, const int* in_sizes, int n_in,
                              void* d_out, int out_size, void* d_ws, size_t ws_size,
                              hipStream_t stream) {
  const float* x  = (const float*)d_in[0];
  const float* Wq = (const float*)d_in[1];
  const float* Wk = (const float*)d_in[2];
  const float* Wv = (const float*)d_in[3];
  const float* Wo = (const float*)d_in[4];
  const float* bo = (const float*)d_in[5];
  const float* W1 = (const float*)d_in[6];
  const float* b1 = (const float*)d_in[7];
  const float* W2 = (const float*)d_in[8];
  const float* b2 = (const float*)d_in[9];
  float* out = (float*)d_out;

  const size_t MB = 1048576;
  char* ws = (char*)d_ws;
  u16* xb    = (u16*)(ws + 0);          // 8MB   (x1b aliases; pbuf aliases at FFN2)
  u16* WqkvT = (u16*)(ws + 8 * MB);     // 6MB   (dead after QKV)
  u16* WoT   = (u16*)(ws + 14 * MB);    // 2MB   (dead after proj)
  u16* W1T   = (u16*)(ws + 16 * MB);    // 8MB   (dead after FFN1)
  u16* W2T   = (u16*)(ws + 24 * MB);    // 8MB   (live through FFN2)
  u16* qkv   = (u16*)(ws + 32 * MB);    // 24MB  (Q/K thirds used; dead after attn)
  u16* attn  = (u16*)(ws + 56 * MB);    // 8MB   (dead after proj)
  float* x1  = (float*)(ws + 64 * MB);  // 16MB  fp32 residual (written by proj, Vt dead)
  u16* Vtb   = (u16*)(ws + 64 * MB);    // 8MB   overlaps x1 (dead before x1 written)
  u16* x1b   = (u16*)(ws + 0);          // alias xb (FFN1 input; dead after FFN1)
  u16* hbuf  = (u16*)(ws + 32 * MB);    // 32MB  alias qkv+attn (FFN2 input)
  u16* pbuf  = (u16*)(ws + 0);          // 16MB  FFN2 split-K partials (x1b dead then)

  // prep: cast + weight transposes to [N][K] bf16
  cast_bf16_kernel<<<(M_ * E_ / 4 + 255) / 256, 256, 0, stream>>>(x, xb, M_ * E_ / 4);
  transpose_cast_kernel<<<dim3(2, 32, 16),  256, 0, stream>>>(Wq, WqkvT,                E_, D_, E_);
  transpose_cast_kernel<<<dim3(2, 32, 16),  256, 0, stream>>>(Wk, WqkvT + 1024 * 1024,  E_, D_, E_);
  transpose_cast_kernel<<<dim3(2, 32, 16),  256, 0, stream>>>(Wv, WqkvT + 2048 * 1024,  E_, D_, E_);
  transpose_cast_kernel<<<dim3(32, 32, 1),  256, 0, stream>>>(Wo, WoT, E_, E_, E_);
  transpose_cast_kernel<<<dim3(128, 32, 1), 256, 0, stream>>>(W1, W1T, E_, DF_, E_);
  transpose_cast_kernel<<<dim3(32, 128, 1), 256, 0, stream>>>(W2, W2T, DF_, E_, DF_);

  // fused QKV GEMM: Q/K -> qkv[M][3072] cols 0..2047; V -> Vtb[E][M] (transposed, fused)
  gemm_bt<128,128,false,false,false,false,true,true><<<dim3(NQKV_ / 128, M_ / 128), 256, 0, stream>>>(
      xb, WqkvT, M_, NQKV_, E_, E_, E_, nullptr, nullptr, nullptr, qkv, Vtb);

  attn_kernel<<<B_ * H_ * (T_ / 128), 512, 0, stream>>>(qkv, Vtb, attn);

  // x1 = x + attn @ Wo + bo  (fp32 residual + bf16 mirror for FFN1)
  gemm_bt<64,128,true,false,true,true,true,false><<<dim3(E_ / 128, M_ / 64), 256, 0, stream>>>(
      attn, WoT, M_, E_, E_, E_, E_, bo, x, x1, x1b, nullptr);
  // h = relu(x1 @ W1 + b1)  (1024 blocks)
  gemm_bt<128,128,true,true,false,false,true,false><<<dim3(DF_ / 128, M_ / 128), 256, 0, stream>>>(
      x1b, W1T, M_, DF_, E_, E_, E_, b1, nullptr, nullptr, hbuf, nullptr);
  // FFN2 split-K: p[z] = h[:, z*2048:] @ W2T[:, z*2048:]^T  (bf16 partials, 512 blocks)
  gemm_bt<128,128,false,false,false,false,true,false><<<dim3(E_ / 128, M_ / 128, 2), 256, 0, stream>>>(
      hbuf, W2T, M_, E_, DF_ / 2, DF_, DF_, nullptr, nullptr, nullptr, pbuf, nullptr);
  // out = x1 + p0 + p1 + b2
  reduce2_kernel<<<M_ * E_ / 4 / 256, 256, 0, stream>>>(x1, pbuf, pbuf + (size_t)M_ * E_, b2, out);
}